// Round 1
// baseline (175.099 us; speedup 1.0000x reference)
//
#include <hip/hip_runtime.h>
#include <hip/hip_bf16.h>

typedef __attribute__((ext_vector_type(8))) short short8;
typedef __attribute__((ext_vector_type(4))) float f32x4;

#define DEVINL static __device__ __forceinline__

DEVINL unsigned short f2bfu(float xv) {
  __hip_bfloat16 h = __float2bfloat16(xv);
  unsigned short u;
  __builtin_memcpy(&u, &h, 2);
  return u;
}

// ---------------------------------------------------------------------------
// 128x128 output tile, 256 threads (2x2 waves of 64x64), BK=64.
// C[m][n] = sum_k A[m][k] * BT[n][k]   (gemm_bt)
// LDS tiles [128][64] bf16, XOR-swizzled: 16B chunk c at row -> c ^ (row&7).
// A is f32 (converted on stage, optionally multiplied by qlds[k]) or bf16.
// ---------------------------------------------------------------------------
template <bool A_F32, bool MULQ>
DEVINL void gemm_tile(const void* Abase, const unsigned short* Bbase,
                      int K, int lda, int ldb,
                      char* ldsA, char* ldsB, const float* qlds,
                      f32x4 acc[4][4])
{
  const int tid  = threadIdx.x;
  const int lane = tid & 63;
  const int wr   = (tid >> 7) & 1;
  const int wc   = (tid >> 6) & 1;

  for (int kk = 0; kk < K; kk += 64) {
#pragma unroll
    for (int i = 0; i < 4; ++i) {
      const int chunk = tid + i * 256;
      const int row   = chunk >> 3;
      const int c     = chunk & 7;
      const int koff  = kk + c * 8;
      const unsigned off = (unsigned)(row * 128) + ((unsigned)(c ^ (row & 7)) << 4);
      if constexpr (A_F32) {
        const float* ap = (const float*)Abase + (size_t)row * lda + koff;
        float4 va = *(const float4*)ap;
        float4 vb = *(const float4*)(ap + 4);
        if constexpr (MULQ) {
          float4 qa = *(const float4*)(qlds + koff);
          float4 qb = *(const float4*)(qlds + koff + 4);
          va.x *= qa.x; va.y *= qa.y; va.z *= qa.z; va.w *= qa.w;
          vb.x *= qb.x; vb.y *= qb.y; vb.z *= qb.z; vb.w *= qb.w;
        }
        short8 o;
        o[0] = (short)f2bfu(va.x); o[1] = (short)f2bfu(va.y);
        o[2] = (short)f2bfu(va.z); o[3] = (short)f2bfu(va.w);
        o[4] = (short)f2bfu(vb.x); o[5] = (short)f2bfu(vb.y);
        o[6] = (short)f2bfu(vb.z); o[7] = (short)f2bfu(vb.w);
        *(short8*)(ldsA + off) = o;
      } else {
        const unsigned short* ap = (const unsigned short*)Abase + (size_t)row * lda + koff;
        *(short8*)(ldsA + off) = *(const short8*)ap;
      }
      const unsigned short* bp = Bbase + (size_t)row * ldb + koff;
      *(short8*)(ldsB + off) = *(const short8*)bp;
    }
    __syncthreads();
#pragma unroll
    for (int s = 0; s < 2; ++s) {
      const int cg = s * 4 + (lane >> 4);
      short8 afr[4], bfr[4];
#pragma unroll
      for (int mi = 0; mi < 4; ++mi) {
        const int row = wr * 64 + mi * 16 + (lane & 15);
        afr[mi] = *(const short8*)(ldsA + row * 128 + ((unsigned)(cg ^ (row & 7)) << 4));
      }
#pragma unroll
      for (int ni = 0; ni < 4; ++ni) {
        const int row = wc * 64 + ni * 16 + (lane & 15);
        bfr[ni] = *(const short8*)(ldsB + row * 128 + ((unsigned)(cg ^ (row & 7)) << 4));
      }
#pragma unroll
      for (int mi = 0; mi < 4; ++mi)
#pragma unroll
        for (int ni = 0; ni < 4; ++ni)
          acc[mi][ni] = __builtin_amdgcn_mfma_f32_16x16x32_bf16(afr[mi], bfr[ni], acc[mi][ni], 0, 0, 0);
    }
    __syncthreads();
  }
}

// ---------------------------------------------------------------------------
// K0a: transpose + convert weight matrices: out[n][k] = bf16(in[k][n])
// grid (NN/32, KK/32), block 256
// ---------------------------------------------------------------------------
__global__ __launch_bounds__(256) void k_transpose_cvt(const float* __restrict__ in,
                                                       unsigned short* __restrict__ out,
                                                       int KK, int NN)
{
  __shared__ float t[32][33];
  const int tx = threadIdx.x & 31, ty = threadIdx.x >> 5;
  const int k0 = blockIdx.y * 32, n0 = blockIdx.x * 32;
#pragma unroll
  for (int i = 0; i < 4; ++i)
    t[ty + i * 8][tx] = in[(size_t)(k0 + ty + i * 8) * NN + n0 + tx];
  __syncthreads();
#pragma unroll
  for (int i = 0; i < 4; ++i)
    out[(size_t)(n0 + ty + i * 8) * KK + k0 + tx] = f2bfu(t[tx][ty + i * 8]);
}

// ---------------------------------------------------------------------------
// K0b: query f32 -> bf16 into x[:, 0:512]   (x rows have stride 1536)
// ---------------------------------------------------------------------------
__global__ __launch_bounds__(256) void k_cvt_query(const float* __restrict__ q,
                                                   unsigned short* __restrict__ x)
{
  const int idx8 = (blockIdx.x * 256 + threadIdx.x) * 8;
  const int row  = idx8 >> 9;
  const int col  = idx8 & 511;
  float4 va = *(const float4*)(q + idx8);
  float4 vb = *(const float4*)(q + idx8 + 4);
  short8 o;
  o[0] = (short)f2bfu(va.x); o[1] = (short)f2bfu(va.y);
  o[2] = (short)f2bfu(va.z); o[3] = (short)f2bfu(va.w);
  o[4] = (short)f2bfu(vb.x); o[5] = (short)f2bfu(vb.y);
  o[6] = (short)f2bfu(vb.z); o[7] = (short)f2bfu(vb.w);
  *(short8*)(x + (size_t)row * 1536 + col) = o;
}

// ---------------------------------------------------------------------------
// K1: projections.  z=0: q=query@WqT+bq (f32); z=1: s_key=src@WsT+bs (f32);
//                   z=2: t_key=trg@WsT+bs (bf16)
// grid (4, 16, 3), block 256
// ---------------------------------------------------------------------------
__global__ __launch_bounds__(256) void k_proj(
    const float* __restrict__ query, const float* __restrict__ src,
    const float* __restrict__ trg,
    const unsigned short* __restrict__ WqT, const unsigned short* __restrict__ WsT,
    const float* __restrict__ bq, const float* __restrict__ bs,
    float* __restrict__ qout, float* __restrict__ skey,
    unsigned short* __restrict__ tkey)
{
  __shared__ __align__(16) char stg[32768];
  const int z = blockIdx.z;
  const float* A = (z == 0) ? query : (z == 1) ? src : trg;
  const unsigned short* BT = (z == 0) ? WqT : WsT;
  const float* bias = (z == 0) ? bq : bs;
  const int brow = blockIdx.y * 128, bcol = blockIdx.x * 128;

  f32x4 acc[4][4] = {};
  gemm_tile<true, false>(A + (size_t)brow * 512, BT + (size_t)bcol * 512,
                         512, 512, 512, stg, stg + 16384, nullptr, acc);

  const int tid = threadIdx.x, lane = tid & 63;
  const int wr = (tid >> 7) & 1, wc = (tid >> 6) & 1;
  const int r0 = wr * 64 + ((lane >> 4) << 2);
  const int c0 = wc * 64 + (lane & 15);
#pragma unroll
  for (int mi = 0; mi < 4; ++mi)
#pragma unroll
    for (int ni = 0; ni < 4; ++ni) {
      const int col = bcol + c0 + ni * 16;
      const float bv = bias[col];
#pragma unroll
      for (int r = 0; r < 4; ++r) {
        const int row = brow + r0 + mi * 16 + r;
        const float v = acc[mi][ni][r] + bv;
        if (z == 0)      qout[(size_t)row * 512 + col] = v;
        else if (z == 1) skey[(size_t)row * 512 + col] = v;
        else             tkey[(size_t)row * 512 + col] = f2bfu(v);
      }
    }
}

// ---------------------------------------------------------------------------
// K2: per-(b,l) trilinear scores + softmax + contexts -> x[:, 512:1536]
// grid 2048, block 256
// ---------------------------------------------------------------------------
__global__ __launch_bounds__(256) void k_score(
    const float* __restrict__ qf, const float* __restrict__ skey,
    const unsigned short* __restrict__ tkey,
    const float* __restrict__ src, const float* __restrict__ trg,
    unsigned short* __restrict__ x)
{
  __shared__ __align__(16) char stg[32768];
  __shared__ float q_lds[512];
  __shared__ float wsp[2][128], wtp[2][128];
  __shared__ float ws_l[128], wt_l[128];
  __shared__ float red[4];
  __shared__ float denom_s;

  // bijective XCD swizzle: same-b blocks land on the same XCD (L2 reuse of
  // skey/tkey/src/trg[b] ~1 MiB across 128 blocks)
  const int raw = blockIdx.x;
  const int swz = (raw & 7) * 256 + (raw >> 3);
  const int b = swz >> 7, l = swz & 127;

  const int tid = threadIdx.x, lane = tid & 63, wid = tid >> 6;
  const int wr = wid >> 1, wc = wid & 1;

  // q row, with log2(e)/sqrt(512) folded in so acc is exp2-ready
  constexpr float SCALE = 0.063758977414048896f; // log2(e)/sqrt(512)
  {
    const float* qrow = qf + (size_t)(b * 128 + l) * 512;
    float2 v = *(const float2*)(qrow + tid * 2);
    q_lds[tid * 2]     = v.x * SCALE;
    q_lds[tid * 2 + 1] = v.y * SCALE;
  }
  __syncthreads();

  f32x4 acc[4][4] = {};
  gemm_tile<true, true>(skey + (size_t)b * (128 * 512),
                        tkey + (size_t)b * (128 * 512),
                        512, 512, 512, stg, stg + 16384, q_lds, acc);

  // ---- global max over all 16384 logits ----
  float m = -1e30f;
#pragma unroll
  for (int mi = 0; mi < 4; ++mi)
#pragma unroll
    for (int ni = 0; ni < 4; ++ni)
#pragma unroll
      for (int r = 0; r < 4; ++r) m = fmaxf(m, acc[mi][ni][r]);
#pragma unroll
  for (int off = 32; off >= 1; off >>= 1) m = fmaxf(m, __shfl_xor(m, off));
  if (lane == 0) red[wid] = m;
  __syncthreads();
  m = fmaxf(fmaxf(red[0], red[1]), fmaxf(red[2], red[3]));

  // ---- exp2 in place ----
#pragma unroll
  for (int mi = 0; mi < 4; ++mi)
#pragma unroll
    for (int ni = 0; ni < 4; ++ni)
#pragma unroll
      for (int r = 0; r < 4; ++r)
        acc[mi][ni][r] = exp2f(acc[mi][ni][r] - m);

  // ---- row sums over t (C layout: col = lane&15, row = (lane>>4)*4 + r) ----
#pragma unroll
  for (int mi = 0; mi < 4; ++mi)
#pragma unroll
    for (int r = 0; r < 4; ++r) {
      float v = acc[mi][0][r] + acc[mi][1][r] + acc[mi][2][r] + acc[mi][3][r];
      v += __shfl_xor(v, 1, 16);
      v += __shfl_xor(v, 2, 16);
      v += __shfl_xor(v, 4, 16);
      v += __shfl_xor(v, 8, 16);
      if ((lane & 15) == 0)
        wsp[wc][wr * 64 + mi * 16 + ((lane >> 4) << 2) + r] = v;
    }
  // ---- col sums over s ----
#pragma unroll
  for (int ni = 0; ni < 4; ++ni) {
    float v = 0.f;
#pragma unroll
    for (int mi = 0; mi < 4; ++mi)
#pragma unroll
      for (int r = 0; r < 4; ++r) v += acc[mi][ni][r];
    v += __shfl_xor(v, 16);
    v += __shfl_xor(v, 32);
    if (lane < 16) wtp[wr][wc * 64 + ni * 16 + lane] = v;
  }
  __syncthreads();
  if (tid < 128) ws_l[tid] = wsp[0][tid] + wsp[1][tid];
  else           wt_l[tid - 128] = wtp[0][tid - 128] + wtp[1][tid - 128];
  __syncthreads();
  if (tid < 64) {
    float v = ws_l[tid] + ws_l[tid + 64];
#pragma unroll
    for (int off = 32; off >= 1; off >>= 1) v += __shfl_xor(v, off);
    if (tid == 0) denom_s = v;
  }
  __syncthreads();
  const float inv = 1.0f / denom_s;

  // ---- contexts: s_ctx = ws·src[b], t_ctx = wt·trg[b] ----
  const float* sb = src + (size_t)b * (128 * 512);
  const float* tb = trg + (size_t)b * (128 * 512);
  float a0 = 0.f, a1 = 0.f, c0v = 0.f, c1v = 0.f;
  for (int s = 0; s < 128; ++s) {
    const float wv = ws_l[s];
    a0 += wv * sb[s * 512 + tid];
    a1 += wv * sb[s * 512 + tid + 256];
  }
  for (int t = 0; t < 128; ++t) {
    const float wv = wt_l[t];
    c0v += wv * tb[t * 512 + tid];
    c1v += wv * tb[t * 512 + tid + 256];
  }
  unsigned short* xr = x + (size_t)(b * 128 + l) * 1536;
  xr[512 + tid]         = f2bfu(a0 * inv);
  xr[512 + tid + 256]   = f2bfu(a1 * inv);
  xr[1024 + tid]        = f2bfu(c0v * inv);
  xr[1024 + tid + 256]  = f2bfu(c1v * inv);
}

// ---------------------------------------------------------------------------
// K3: out = x @ WoT^T + bo   (x bf16 [2048][1536], WoT bf16 [512][1536])
// grid (4, 16), block 256
// ---------------------------------------------------------------------------
__global__ __launch_bounds__(256) void k_out(const unsigned short* __restrict__ x,
                                             const unsigned short* __restrict__ WoT,
                                             const float* __restrict__ bo,
                                             float* __restrict__ out)
{
  __shared__ __align__(16) char stg[32768];
  const int brow = blockIdx.y * 128, bcol = blockIdx.x * 128;
  f32x4 acc[4][4] = {};
  gemm_tile<false, false>(x + (size_t)brow * 1536, WoT + (size_t)bcol * 1536,
                          1536, 1536, 1536, stg, stg + 16384, nullptr, acc);
  const int tid = threadIdx.x, lane = tid & 63;
  const int wr = (tid >> 7) & 1, wc = (tid >> 6) & 1;
  const int r0 = wr * 64 + ((lane >> 4) << 2);
  const int c0 = wc * 64 + (lane & 15);
#pragma unroll
  for (int mi = 0; mi < 4; ++mi)
#pragma unroll
    for (int ni = 0; ni < 4; ++ni) {
      const int col = bcol + c0 + ni * 16;
      const float bv = bo[col];
#pragma unroll
      for (int r = 0; r < 4; ++r) {
        const int row = brow + r0 + mi * 16 + r;
        out[(size_t)row * 512 + col] = acc[mi][ni][r] + bv;
      }
    }
}

// ---------------------------------------------------------------------------
extern "C" void kernel_launch(void* const* d_in, const int* in_sizes, int n_in,
                              void* d_out, int out_size, void* d_ws, size_t ws_size,
                              hipStream_t stream)
{
  (void)in_sizes; (void)n_in; (void)out_size; (void)ws_size;
  const float* query = (const float*)d_in[0];
  const float* src   = (const float*)d_in[1];
  const float* trg   = (const float*)d_in[2];
  const float* Wq    = (const float*)d_in[3];
  const float* bq    = (const float*)d_in[4];
  const float* Ws    = (const float*)d_in[5];
  const float* bs    = (const float*)d_in[6];
  const float* Wo    = (const float*)d_in[7];
  const float* bo    = (const float*)d_in[8];
  float* out = (float*)d_out;

  char* w = (char*)d_ws;
  float*          qf   = (float*)(w);                               // 4 MiB f32 [2048][512]
  float*          skey = (float*)(w + (4u << 20));                  // 4 MiB f32 [2048][512]
  unsigned short* tkey = (unsigned short*)(w + (8u << 20));         // 2 MiB bf16 [2048][512]
  unsigned short* x    = (unsigned short*)(w + (10u << 20));        // 6 MiB bf16 [2048][1536]
  unsigned short* WqT  = (unsigned short*)(w + (16u << 20));        // 0.5 MiB bf16 [512][512]
  unsigned short* WsT  = (unsigned short*)(w + (16u << 20) + 512 * 512 * 2);
  unsigned short* WoT  = (unsigned short*)(w + (17u << 20));        // 1.5 MiB bf16 [512][1536]

  k_transpose_cvt<<<dim3(16, 16), 256, 0, stream>>>(Wq, WqT, 512, 512);
  k_transpose_cvt<<<dim3(16, 16), 256, 0, stream>>>(Ws, WsT, 512, 512);
  k_transpose_cvt<<<dim3(16, 48), 256, 0, stream>>>(Wo, WoT, 1536, 512);
  k_cvt_query<<<512, 256, 0, stream>>>(query, x);
  k_proj<<<dim3(4, 16, 3), 256, 0, stream>>>(query, src, trg, WqT, WsT, bq, bs, qf, skey, tkey);
  k_score<<<2048, 256, 0, stream>>>(qf, skey, tkey, src, trg, x);
  k_out<<<dim3(4, 16), 256, 0, stream>>>(x, WoT, bo, out);
}

// Round 2
// 134.312 us; speedup vs baseline: 1.3037x; 1.3037x over previous
//
#include <hip/hip_runtime.h>
#include <hip/hip_bf16.h>

typedef __attribute__((ext_vector_type(8))) short short8;
typedef __attribute__((ext_vector_type(4))) short short4v;
typedef __attribute__((ext_vector_type(4))) float f32x4;
typedef __attribute__((ext_vector_type(8))) _Float16 half8;

#define DEVINL static __device__ __forceinline__

constexpr float SCORE_SCALE = 0.063758977414048896f; // log2(e)/sqrt(512)

DEVINL unsigned short f2bfu(float xv) {
  __hip_bfloat16 h = __float2bfloat16(xv);
  unsigned short u;
  __builtin_memcpy(&u, &h, 2);
  return u;
}

typedef const __attribute__((address_space(1))) void gv_t;
typedef __attribute__((address_space(3))) void lv_t;
DEVINL void gload16(const void* g, void* l) {
  __builtin_amdgcn_global_load_lds((gv_t*)g, (lv_t*)l, 16, 0, 0);
}

// ---------------------------------------------------------------------------
// bf16 gemm_bt tile: 128x128 out, 256 thr (2x2 waves of 64x64), BK=64.
// LDS [128][64] bf16, XOR-swizzle: 16B chunk c at row r -> c ^ (r&7).
// ---------------------------------------------------------------------------
template <bool A_F32>
DEVINL void gemm_tile(const void* Abase, const unsigned short* Bbase,
                      int K, int lda, int ldb,
                      char* ldsA, char* ldsB, f32x4 acc[4][4])
{
  const int tid  = threadIdx.x;
  const int lane = tid & 63;
  const int wr   = (tid >> 7) & 1;
  const int wc   = (tid >> 6) & 1;

  for (int kk = 0; kk < K; kk += 64) {
#pragma unroll
    for (int i = 0; i < 4; ++i) {
      const int chunk = tid + i * 256;
      const int row   = chunk >> 3;
      const int c     = chunk & 7;
      const int koff  = kk + c * 8;
      const unsigned off = (unsigned)(row * 128) + ((unsigned)(c ^ (row & 7)) << 4);
      if constexpr (A_F32) {
        const float* ap = (const float*)Abase + (size_t)row * lda + koff;
        float4 va = *(const float4*)ap;
        float4 vb = *(const float4*)(ap + 4);
        short8 o;
        o[0] = (short)f2bfu(va.x); o[1] = (short)f2bfu(va.y);
        o[2] = (short)f2bfu(va.z); o[3] = (short)f2bfu(va.w);
        o[4] = (short)f2bfu(vb.x); o[5] = (short)f2bfu(vb.y);
        o[6] = (short)f2bfu(vb.z); o[7] = (short)f2bfu(vb.w);
        *(short8*)(ldsA + off) = o;
      } else {
        const unsigned short* ap = (const unsigned short*)Abase + (size_t)row * lda + koff;
        *(short8*)(ldsA + off) = *(const short8*)ap;
      }
      const unsigned short* bp = Bbase + (size_t)row * ldb + koff;
      *(short8*)(ldsB + off) = *(const short8*)bp;
    }
    __syncthreads();
#pragma unroll
    for (int s = 0; s < 2; ++s) {
      const int cg = s * 4 + (lane >> 4);
      short8 afr[4], bfr[4];
#pragma unroll
      for (int mi = 0; mi < 4; ++mi) {
        const int row = wr * 64 + mi * 16 + (lane & 15);
        afr[mi] = *(const short8*)(ldsA + row * 128 + ((unsigned)(cg ^ (row & 7)) << 4));
      }
#pragma unroll
      for (int ni = 0; ni < 4; ++ni) {
        const int row = wc * 64 + ni * 16 + (lane & 15);
        bfr[ni] = *(const short8*)(ldsB + row * 128 + ((unsigned)(cg ^ (row & 7)) << 4));
      }
#pragma unroll
      for (int mi = 0; mi < 4; ++mi)
#pragma unroll
        for (int ni = 0; ni < 4; ++ni)
          acc[mi][ni] = __builtin_amdgcn_mfma_f32_16x16x32_bf16(afr[mi], bfr[ni], acc[mi][ni], 0, 0, 0);
    }
    __syncthreads();
  }
}

// ---------------------------------------------------------------------------
// K0a: transpose + convert weights: out[n][k] = bf16(in[k][n])
// ---------------------------------------------------------------------------
__global__ __launch_bounds__(256) void k_transpose_cvt(const float* __restrict__ in,
                                                       unsigned short* __restrict__ out,
                                                       int KK, int NN)
{
  __shared__ float t[32][33];
  const int tx = threadIdx.x & 31, ty = threadIdx.x >> 5;
  const int k0 = blockIdx.y * 32, n0 = blockIdx.x * 32;
#pragma unroll
  for (int i = 0; i < 4; ++i)
    t[ty + i * 8][tx] = in[(size_t)(k0 + ty + i * 8) * NN + n0 + tx];
  __syncthreads();
#pragma unroll
  for (int i = 0; i < 4; ++i)
    out[(size_t)(n0 + ty + i * 8) * KK + k0 + tx] = f2bfu(t[tx][ty + i * 8]);
}

// ---------------------------------------------------------------------------
// K0b: query f32 -> bf16 into x[:, 0:512]
// ---------------------------------------------------------------------------
__global__ __launch_bounds__(256) void k_cvt_query(const float* __restrict__ q,
                                                   unsigned short* __restrict__ x)
{
  const int idx8 = (blockIdx.x * 256 + threadIdx.x) * 8;
  const int row  = idx8 >> 9;
  const int col  = idx8 & 511;
  float4 va = *(const float4*)(q + idx8);
  float4 vb = *(const float4*)(q + idx8 + 4);
  short8 o;
  o[0] = (short)f2bfu(va.x); o[1] = (short)f2bfu(va.y);
  o[2] = (short)f2bfu(va.z); o[3] = (short)f2bfu(va.w);
  o[4] = (short)f2bfu(vb.x); o[5] = (short)f2bfu(vb.y);
  o[6] = (short)f2bfu(vb.z); o[7] = (short)f2bfu(vb.w);
  *(short8*)(x + (size_t)row * 1536 + col) = o;
}

// ---------------------------------------------------------------------------
// K1: projections -> fp16.  z=0: qh=(query@Wq+bq)*SCALE; z=1: skh=src@Ws+bs;
//                           z=2: tkh=trg@Ws+bs
// ---------------------------------------------------------------------------
__global__ __launch_bounds__(256) void k_proj(
    const float* __restrict__ query, const float* __restrict__ src,
    const float* __restrict__ trg,
    const unsigned short* __restrict__ WqT, const unsigned short* __restrict__ WsT,
    const float* __restrict__ bq, const float* __restrict__ bs,
    _Float16* __restrict__ qh, _Float16* __restrict__ skh,
    _Float16* __restrict__ tkh)
{
  __shared__ __align__(16) char stg[32768];
  const int z = blockIdx.z;
  const float* A = (z == 0) ? query : (z == 1) ? src : trg;
  const unsigned short* BT = (z == 0) ? WqT : WsT;
  const float* bias = (z == 0) ? bq : bs;
  const int brow = blockIdx.y * 128, bcol = blockIdx.x * 128;

  f32x4 acc[4][4] = {};
  gemm_tile<true>(A + (size_t)brow * 512, BT + (size_t)bcol * 512,
                  512, 512, 512, stg, stg + 16384, acc);

  const int tid = threadIdx.x, lane = tid & 63;
  const int wr = (tid >> 7) & 1, wc = (tid >> 6) & 1;
  const int r0 = wr * 64 + ((lane >> 4) << 2);
  const int c0 = wc * 64 + (lane & 15);
#pragma unroll
  for (int mi = 0; mi < 4; ++mi)
#pragma unroll
    for (int ni = 0; ni < 4; ++ni) {
      const int col = bcol + c0 + ni * 16;
      const float bv = bias[col];
#pragma unroll
      for (int r = 0; r < 4; ++r) {
        const int row = brow + r0 + mi * 16 + r;
        const float v = acc[mi][ni][r] + bv;
        if (z == 0)      qh[(size_t)row * 512 + col] = (_Float16)(v * SCORE_SCALE);
        else if (z == 1) skh[(size_t)row * 512 + col] = (_Float16)v;
        else             tkh[(size_t)row * 512 + col] = (_Float16)v;
      }
    }
}

// ---------------------------------------------------------------------------
// K2: per-(b, l-pair) trilinear scores + softmax + contexts -> x[:, 512:1536]
// NL=2 l's per block; fp16 operands; global_load_lds staging (linear LDS dest,
// pre-swizzled global source, swizzled reads); double-buffered.
// grid 1024, block 256
// ---------------------------------------------------------------------------
__global__ __launch_bounds__(256, 2) void k_score(
    const _Float16* __restrict__ qh, const _Float16* __restrict__ skh,
    const _Float16* __restrict__ tkh,
    const float* __restrict__ src, const float* __restrict__ trg,
    unsigned short* __restrict__ x)
{
  __shared__ __align__(16) _Float16 buf[2][2][128 * 64]; // [dbuf][S/T][row*64+..]
  __shared__ __align__(16) _Float16 qlds[2][512];
  __shared__ float wsp[2][2][128], wtp[2][2][128];
  __shared__ float wfin[2][2][128];   // [l][0=ws,1=wt][128]
  __shared__ float red[2][4];
  __shared__ float denom[2];

  // bijective XCD swizzle (1024 % 8 == 0): same-b blocks share an XCD L2
  const int raw = blockIdx.x;
  const int swz = (raw & 7) * 128 + (raw >> 3);
  const int b = swz >> 6, l0 = (swz & 63) * 2;

  const int tid = threadIdx.x, lane = tid & 63, wid = tid >> 6;
  const int wr = wid >> 1, wc = wid & 1;

  const _Float16* skb = skh + (size_t)b * 65536;
  const _Float16* tkb = tkh + (size_t)b * 65536;

  // per-lane stage source offsets (kk-invariant): chunk ci = wid*256+j*64+lane
  int soff[4];
#pragma unroll
  for (int j = 0; j < 4; ++j) {
    const int ci = wid * 256 + j * 64 + lane;
    const int row = ci >> 3, p = ci & 7;
    soff[j] = row * 512 + ((p ^ (row & 7)) << 3);
  }

#define STAGE(dst, kk)                                                          \
  {                                                                             \
    _Float16* dS = &buf[dst][0][0];                                             \
    _Float16* dT = &buf[dst][1][0];                                             \
    const int dbase = wid * 2048;                                               \
    _Pragma("unroll")                                                           \
    for (int j = 0; j < 4; ++j)                                                 \
      gload16(skb + soff[j] + (kk), dS + dbase + j * 512);                      \
    _Pragma("unroll")                                                           \
    for (int j = 0; j < 4; ++j)                                                 \
      gload16(tkb + soff[j] + (kk), dT + dbase + j * 512);                      \
  }

  STAGE(0, 0);
  { // load two q rows (pre-scaled fp16) into LDS
    const int li = tid >> 7;
    const int e  = (tid & 127) * 4;
    *(short4v*)(&qlds[li][e]) =
        *(const short4v*)(qh + (size_t)(b * 128 + l0 + li) * 512 + e);
  }
  __syncthreads();

  f32x4 acc[2][4][4] = {};
  int cur = 0;
  for (int t = 0; t < 8; ++t) {
    if (t < 7) STAGE(cur ^ 1, (t + 1) * 64);
    const _Float16* bufS = &buf[cur][0][0];
    const _Float16* bufT = &buf[cur][1][0];
    const int kk = t * 64;
#pragma unroll
    for (int s = 0; s < 2; ++s) {
      const int cg = s * 4 + (lane >> 4);
      half8 qv[2];
      qv[0] = *(const half8*)(&qlds[0][kk + cg * 8]);
      qv[1] = *(const half8*)(&qlds[1][kk + cg * 8]);
      half8 sfr[4], tfr[4];
#pragma unroll
      for (int mi = 0; mi < 4; ++mi) {
        const int row = wr * 64 + mi * 16 + (lane & 15);
        sfr[mi] = *(const half8*)(bufS + row * 64 + ((cg ^ (row & 7)) << 3));
      }
#pragma unroll
      for (int ni = 0; ni < 4; ++ni) {
        const int row = wc * 64 + ni * 16 + (lane & 15);
        tfr[ni] = *(const half8*)(bufT + row * 64 + ((cg ^ (row & 7)) << 3));
      }
#pragma unroll
      for (int li = 0; li < 2; ++li)
#pragma unroll
        for (int mi = 0; mi < 4; ++mi) {
          half8 a = sfr[mi] * qv[li];
#pragma unroll
          for (int ni = 0; ni < 4; ++ni)
            acc[li][mi][ni] =
                __builtin_amdgcn_mfma_f32_16x16x32_f16(a, tfr[ni], acc[li][mi][ni], 0, 0, 0);
        }
    }
    __syncthreads();
    cur ^= 1;
  }

  // ---- per-l global max ----
  float mx[2] = {-1e30f, -1e30f};
#pragma unroll
  for (int li = 0; li < 2; ++li)
#pragma unroll
    for (int mi = 0; mi < 4; ++mi)
#pragma unroll
      for (int ni = 0; ni < 4; ++ni)
#pragma unroll
        for (int r = 0; r < 4; ++r) mx[li] = fmaxf(mx[li], acc[li][mi][ni][r]);
#pragma unroll
  for (int li = 0; li < 2; ++li) {
#pragma unroll
    for (int off = 32; off >= 1; off >>= 1) mx[li] = fmaxf(mx[li], __shfl_xor(mx[li], off));
    if (lane == 0) red[li][wid] = mx[li];
  }
  __syncthreads();
  mx[0] = fmaxf(fmaxf(red[0][0], red[0][1]), fmaxf(red[0][2], red[0][3]));
  mx[1] = fmaxf(fmaxf(red[1][0], red[1][1]), fmaxf(red[1][2], red[1][3]));

  // ---- exp2 in place ----
#pragma unroll
  for (int li = 0; li < 2; ++li)
#pragma unroll
    for (int mi = 0; mi < 4; ++mi)
#pragma unroll
      for (int ni = 0; ni < 4; ++ni)
#pragma unroll
        for (int r = 0; r < 4; ++r)
          acc[li][mi][ni][r] = exp2f(acc[li][mi][ni][r] - mx[li]);

  // ---- row sums over t (C layout: col=lane&15, row=(lane>>4)*4+r) ----
#pragma unroll
  for (int li = 0; li < 2; ++li)
#pragma unroll
    for (int mi = 0; mi < 4; ++mi)
#pragma unroll
      for (int r = 0; r < 4; ++r) {
        float v = acc[li][mi][0][r] + acc[li][mi][1][r] + acc[li][mi][2][r] + acc[li][mi][3][r];
        v += __shfl_xor(v, 1, 16);
        v += __shfl_xor(v, 2, 16);
        v += __shfl_xor(v, 4, 16);
        v += __shfl_xor(v, 8, 16);
        if ((lane & 15) == 0)
          wsp[li][wc][wr * 64 + mi * 16 + ((lane >> 4) << 2) + r] = v;
      }
  // ---- col sums over s ----
#pragma unroll
  for (int li = 0; li < 2; ++li)
#pragma unroll
    for (int ni = 0; ni < 4; ++ni) {
      float v = 0.f;
#pragma unroll
      for (int mi = 0; mi < 4; ++mi)
#pragma unroll
        for (int r = 0; r < 4; ++r) v += acc[li][mi][ni][r];
      v += __shfl_xor(v, 16);
      v += __shfl_xor(v, 32);
      if (lane < 16) wtp[li][wr][wc * 64 + ni * 16 + lane] = v;
    }
  __syncthreads();
  if (tid < 128) {
    wfin[0][0][tid] = wsp[0][0][tid] + wsp[0][1][tid];
    wfin[1][0][tid] = wsp[1][0][tid] + wsp[1][1][tid];
  } else {
    const int u = tid - 128;
    wfin[0][1][u] = wtp[0][0][u] + wtp[0][1][u];
    wfin[1][1][u] = wtp[1][0][u] + wtp[1][1][u];
  }
  __syncthreads();
  if (wid < 2) {
    float v = wfin[wid][0][lane] + wfin[wid][0][lane + 64];
#pragma unroll
    for (int off = 32; off >= 1; off >>= 1) v += __shfl_xor(v, off);
    if (lane == 0) denom[wid] = v;
  }
  __syncthreads();
  const float inv0 = 1.0f / denom[0], inv1 = 1.0f / denom[1];

  // ---- contexts (shared src/trg loads across both l's) ----
  const float* sb = src + (size_t)b * 65536;
  const float* tb = trg + (size_t)b * 65536;
  float cs[2][2] = {}, ct[2][2] = {};
  for (int s = 0; s < 128; ++s) {
    const float v0 = sb[s * 512 + tid], v1 = sb[s * 512 + tid + 256];
    const float w0 = wfin[0][0][s], w1 = wfin[1][0][s];
    cs[0][0] += w0 * v0; cs[0][1] += w0 * v1;
    cs[1][0] += w1 * v0; cs[1][1] += w1 * v1;
  }
  for (int t = 0; t < 128; ++t) {
    const float v0 = tb[t * 512 + tid], v1 = tb[t * 512 + tid + 256];
    const float w0 = wfin[0][1][t], w1 = wfin[1][1][t];
    ct[0][0] += w0 * v0; ct[0][1] += w0 * v1;
    ct[1][0] += w1 * v0; ct[1][1] += w1 * v1;
  }
  unsigned short* xr0 = x + (size_t)(b * 128 + l0) * 1536;
  unsigned short* xr1 = xr0 + 1536;
  xr0[512 + tid]        = f2bfu(cs[0][0] * inv0);
  xr0[768 + tid]        = f2bfu(cs[0][1] * inv0);
  xr0[1024 + tid]       = f2bfu(ct[0][0] * inv0);
  xr0[1280 + tid]       = f2bfu(ct[0][1] * inv0);
  xr1[512 + tid]        = f2bfu(cs[1][0] * inv1);
  xr1[768 + tid]        = f2bfu(cs[1][1] * inv1);
  xr1[1024 + tid]       = f2bfu(ct[1][0] * inv1);
  xr1[1280 + tid]       = f2bfu(ct[1][1] * inv1);
#undef STAGE
}

// ---------------------------------------------------------------------------
// K3: out = x @ WoT^T + bo
// ---------------------------------------------------------------------------
__global__ __launch_bounds__(256) void k_out(const unsigned short* __restrict__ x,
                                             const unsigned short* __restrict__ WoT,
                                             const float* __restrict__ bo,
                                             float* __restrict__ out)
{
  __shared__ __align__(16) char stg[32768];
  const int brow = blockIdx.y * 128, bcol = blockIdx.x * 128;
  f32x4 acc[4][4] = {};
  gemm_tile<false>(x + (size_t)brow * 1536, WoT + (size_t)bcol * 1536,
                   1536, 1536, 1536, stg, stg + 16384, acc);
  const int tid = threadIdx.x, lane = tid & 63;
  const int wr = (tid >> 7) & 1, wc = (tid >> 6) & 1;
  const int r0 = wr * 64 + ((lane >> 4) << 2);
  const int c0 = wc * 64 + (lane & 15);
#pragma unroll
  for (int mi = 0; mi < 4; ++mi)
#pragma unroll
    for (int ni = 0; ni < 4; ++ni) {
      const int col = bcol + c0 + ni * 16;
      const float bv = bo[col];
#pragma unroll
      for (int r = 0; r < 4; ++r) {
        const int row = brow + r0 + mi * 16 + r;
        out[(size_t)row * 512 + col] = acc[mi][ni][r] + bv;
      }
    }
}

// ---------------------------------------------------------------------------
extern "C" void kernel_launch(void* const* d_in, const int* in_sizes, int n_in,
                              void* d_out, int out_size, void* d_ws, size_t ws_size,
                              hipStream_t stream)
{
  (void)in_sizes; (void)n_in; (void)out_size; (void)ws_size;
  const float* query = (const float*)d_in[0];
  const float* src   = (const float*)d_in[1];
  const float* trg   = (const float*)d_in[2];
  const float* Wq    = (const float*)d_in[3];
  const float* bq    = (const float*)d_in[4];
  const float* Ws    = (const float*)d_in[5];
  const float* bs    = (const float*)d_in[6];
  const float* Wo    = (const float*)d_in[7];
  const float* bo    = (const float*)d_in[8];
  float* out = (float*)d_out;

  char* w = (char*)d_ws;
  _Float16*       qh   = (_Float16*)(w);                            // 2 MiB
  _Float16*       skh  = (_Float16*)(w + (2u << 20));               // 2 MiB
  _Float16*       tkh  = (_Float16*)(w + (4u << 20));               // 2 MiB
  unsigned short* x    = (unsigned short*)(w + (6u << 20));         // 6 MiB bf16 [2048][1536]
  unsigned short* WqT  = (unsigned short*)(w + (12u << 20));        // 0.5 MiB
  unsigned short* WsT  = (unsigned short*)(w + (12u << 20) + 512 * 512 * 2);
  unsigned short* WoT  = (unsigned short*)(w + (13u << 20));        // 1.5 MiB

  k_transpose_cvt<<<dim3(16, 16), 256, 0, stream>>>(Wq, WqT, 512, 512);
  k_transpose_cvt<<<dim3(16, 16), 256, 0, stream>>>(Ws, WsT, 512, 512);
  k_transpose_cvt<<<dim3(16, 48), 256, 0, stream>>>(Wo, WoT, 1536, 512);
  k_cvt_query<<<512, 256, 0, stream>>>(query, x);
  k_proj<<<dim3(4, 16, 3), 256, 0, stream>>>(query, src, trg, WqT, WsT, bq, bs, qh, skh, tkh);
  k_score<<<1024, 256, 0, stream>>>(qh, skh, tkh, src, trg, x);
  k_out<<<dim3(4, 16), 256, 0, stream>>>(x, WoT, bo, out);
}

// Round 3
// 124.168 us; speedup vs baseline: 1.4102x; 1.0817x over previous
//
#include <hip/hip_runtime.h>
#include <hip/hip_bf16.h>

typedef __attribute__((ext_vector_type(8))) short short8;
typedef __attribute__((ext_vector_type(4))) short short4v;
typedef __attribute__((ext_vector_type(4))) float f32x4;
typedef __attribute__((ext_vector_type(8))) _Float16 half8;

#define DEVINL static __device__ __forceinline__

constexpr float SCORE_SCALE = 0.063758977414048896f; // log2(e)/sqrt(512)

DEVINL unsigned short f2bfu(float xv) {
  __hip_bfloat16 h = __float2bfloat16(xv);
  unsigned short u;
  __builtin_memcpy(&u, &h, 2);
  return u;
}

typedef const __attribute__((address_space(1))) void gv_t;
typedef __attribute__((address_space(3))) void lv_t;
DEVINL void gload16(const void* g, void* l) {
  __builtin_amdgcn_global_load_lds((gv_t*)g, (lv_t*)l, 16, 0, 0);
}

// ---------------------------------------------------------------------------
// bf16 gemm_bt tile: 128x128 out, 256 thr (2x2 waves of 64x64), BK=64.
// LDS [128][64] bf16, XOR-swizzle: 16B chunk c at row r -> c ^ (r&7).
// ---------------------------------------------------------------------------
template <bool A_F32>
DEVINL void gemm_tile(const void* Abase, const unsigned short* Bbase,
                      int K, int lda, int ldb,
                      char* ldsA, char* ldsB, f32x4 acc[4][4])
{
  const int tid  = threadIdx.x;
  const int lane = tid & 63;
  const int wr   = (tid >> 7) & 1;
  const int wc   = (tid >> 6) & 1;

  for (int kk = 0; kk < K; kk += 64) {
#pragma unroll
    for (int i = 0; i < 4; ++i) {
      const int chunk = tid + i * 256;
      const int row   = chunk >> 3;
      const int c     = chunk & 7;
      const int koff  = kk + c * 8;
      const unsigned off = (unsigned)(row * 128) + ((unsigned)(c ^ (row & 7)) << 4);
      if constexpr (A_F32) {
        const float* ap = (const float*)Abase + (size_t)row * lda + koff;
        float4 va = *(const float4*)ap;
        float4 vb = *(const float4*)(ap + 4);
        short8 o;
        o[0] = (short)f2bfu(va.x); o[1] = (short)f2bfu(va.y);
        o[2] = (short)f2bfu(va.z); o[3] = (short)f2bfu(va.w);
        o[4] = (short)f2bfu(vb.x); o[5] = (short)f2bfu(vb.y);
        o[6] = (short)f2bfu(vb.z); o[7] = (short)f2bfu(vb.w);
        *(short8*)(ldsA + off) = o;
      } else {
        const unsigned short* ap = (const unsigned short*)Abase + (size_t)row * lda + koff;
        *(short8*)(ldsA + off) = *(const short8*)ap;
      }
      const unsigned short* bp = Bbase + (size_t)row * ldb + koff;
      *(short8*)(ldsB + off) = *(const short8*)bp;
    }
    __syncthreads();
#pragma unroll
    for (int s = 0; s < 2; ++s) {
      const int cg = s * 4 + (lane >> 4);
      short8 afr[4], bfr[4];
#pragma unroll
      for (int mi = 0; mi < 4; ++mi) {
        const int row = wr * 64 + mi * 16 + (lane & 15);
        afr[mi] = *(const short8*)(ldsA + row * 128 + ((unsigned)(cg ^ (row & 7)) << 4));
      }
#pragma unroll
      for (int ni = 0; ni < 4; ++ni) {
        const int row = wc * 64 + ni * 16 + (lane & 15);
        bfr[ni] = *(const short8*)(ldsB + row * 128 + ((unsigned)(cg ^ (row & 7)) << 4));
      }
#pragma unroll
      for (int mi = 0; mi < 4; ++mi)
#pragma unroll
        for (int ni = 0; ni < 4; ++ni)
          acc[mi][ni] = __builtin_amdgcn_mfma_f32_16x16x32_bf16(afr[mi], bfr[ni], acc[mi][ni], 0, 0, 0);
    }
    __syncthreads();
  }
}

// ---------------------------------------------------------------------------
// K0a: batched transpose + convert: out[z][n][k] = bf16(in[z][k][n])
// grid (NN/32, KK/32, batch), block 256
// ---------------------------------------------------------------------------
__global__ __launch_bounds__(256) void k_transpose_cvt(const float* __restrict__ in,
                                                       unsigned short* __restrict__ out,
                                                       int KK, int NN)
{
  __shared__ float t[32][33];
  const size_t bo = (size_t)blockIdx.z * KK * NN;
  const int tx = threadIdx.x & 31, ty = threadIdx.x >> 5;
  const int k0 = blockIdx.y * 32, n0 = blockIdx.x * 32;
#pragma unroll
  for (int i = 0; i < 4; ++i)
    t[ty + i * 8][tx] = in[bo + (size_t)(k0 + ty + i * 8) * NN + n0 + tx];
  __syncthreads();
#pragma unroll
  for (int i = 0; i < 4; ++i)
    out[bo + (size_t)(n0 + ty + i * 8) * KK + k0 + tx] = f2bfu(t[tx][ty + i * 8]);
}

// ---------------------------------------------------------------------------
// K0b: query f32 -> bf16 into x[:, 0:512]
// ---------------------------------------------------------------------------
__global__ __launch_bounds__(256) void k_cvt_query(const float* __restrict__ q,
                                                   unsigned short* __restrict__ x)
{
  const int idx8 = (blockIdx.x * 256 + threadIdx.x) * 8;
  const int row  = idx8 >> 9;
  const int col  = idx8 & 511;
  float4 va = *(const float4*)(q + idx8);
  float4 vb = *(const float4*)(q + idx8 + 4);
  short8 o;
  o[0] = (short)f2bfu(va.x); o[1] = (short)f2bfu(va.y);
  o[2] = (short)f2bfu(va.z); o[3] = (short)f2bfu(va.w);
  o[4] = (short)f2bfu(vb.x); o[5] = (short)f2bfu(vb.y);
  o[6] = (short)f2bfu(vb.z); o[7] = (short)f2bfu(vb.w);
  *(short8*)(x + (size_t)row * 1536 + col) = o;
}

// ---------------------------------------------------------------------------
// K1: projections -> fp16.  z=0: qh=(query@Wq+bq)*SCALE; z=1: skh=src@Ws+bs;
//                           z=2: tkh=trg@Ws+bs
// ---------------------------------------------------------------------------
__global__ __launch_bounds__(256) void k_proj(
    const float* __restrict__ query, const float* __restrict__ src,
    const float* __restrict__ trg,
    const unsigned short* __restrict__ WqT, const unsigned short* __restrict__ WsT,
    const float* __restrict__ bq, const float* __restrict__ bs,
    _Float16* __restrict__ qh, _Float16* __restrict__ skh,
    _Float16* __restrict__ tkh)
{
  __shared__ __align__(16) char stg[32768];
  const int z = blockIdx.z;
  const float* A = (z == 0) ? query : (z == 1) ? src : trg;
  const unsigned short* BT = (z == 0) ? WqT : WsT;
  const float* bias = (z == 0) ? bq : bs;
  const int brow = blockIdx.y * 128, bcol = blockIdx.x * 128;

  f32x4 acc[4][4] = {};
  gemm_tile<true>(A + (size_t)brow * 512, BT + (size_t)bcol * 512,
                  512, 512, 512, stg, stg + 16384, acc);

  const int tid = threadIdx.x, lane = tid & 63;
  const int wr = (tid >> 7) & 1, wc = (tid >> 6) & 1;
  const int r0 = wr * 64 + ((lane >> 4) << 2);
  const int c0 = wc * 64 + (lane & 15);
#pragma unroll
  for (int mi = 0; mi < 4; ++mi)
#pragma unroll
    for (int ni = 0; ni < 4; ++ni) {
      const int col = bcol + c0 + ni * 16;
      const float bv = bias[col];
#pragma unroll
      for (int r = 0; r < 4; ++r) {
        const int row = brow + r0 + mi * 16 + r;
        const float v = acc[mi][ni][r] + bv;
        if (z == 0)      qh[(size_t)row * 512 + col] = (_Float16)(v * SCORE_SCALE);
        else if (z == 1) skh[(size_t)row * 512 + col] = (_Float16)v;
        else             tkh[(size_t)row * 512 + col] = (_Float16)v;
      }
    }
}

// ---------------------------------------------------------------------------
// K2: per-(b, l-pair) trilinear scores + softmax -> normalized ws/wt (bf16)
// NL=2 l's per block; fp16 operands; global_load_lds staging; double-buffered.
// grid 1024, block 256.  wct[b][side][l][s] bf16.
// ---------------------------------------------------------------------------
__global__ __launch_bounds__(256, 2) void k_score(
    const _Float16* __restrict__ qh, const _Float16* __restrict__ skh,
    const _Float16* __restrict__ tkh,
    unsigned short* __restrict__ wct)
{
  __shared__ __align__(16) _Float16 buf[2][2][128 * 64]; // [dbuf][S/T][row*64+..]
  __shared__ __align__(16) _Float16 qlds[2][512];
  __shared__ float wsp[2][2][128], wtp[2][2][128];
  __shared__ float wfin[2][2][128];   // [l][0=ws,1=wt][128]
  __shared__ float red[2][4];
  __shared__ float denom[2];

  // bijective XCD swizzle (1024 % 8 == 0): same-b blocks share an XCD L2
  const int raw = blockIdx.x;
  const int swz = (raw & 7) * 128 + (raw >> 3);
  const int b = swz >> 6, l0 = (swz & 63) * 2;

  const int tid = threadIdx.x, lane = tid & 63, wid = tid >> 6;
  const int wr = wid >> 1, wc = wid & 1;

  const _Float16* skb = skh + (size_t)b * 65536;
  const _Float16* tkb = tkh + (size_t)b * 65536;

  // per-lane stage source offsets (kk-invariant): chunk ci = wid*256+j*64+lane
  int soff[4];
#pragma unroll
  for (int j = 0; j < 4; ++j) {
    const int ci = wid * 256 + j * 64 + lane;
    const int row = ci >> 3, p = ci & 7;
    soff[j] = row * 512 + ((p ^ (row & 7)) << 3);
  }

#define STAGE(dst, kk)                                                          \
  {                                                                             \
    _Float16* dS = &buf[dst][0][0];                                             \
    _Float16* dT = &buf[dst][1][0];                                             \
    const int dbase = wid * 2048;                                               \
    _Pragma("unroll")                                                           \
    for (int j = 0; j < 4; ++j)                                                 \
      gload16(skb + soff[j] + (kk), dS + dbase + j * 512);                      \
    _Pragma("unroll")                                                           \
    for (int j = 0; j < 4; ++j)                                                 \
      gload16(tkb + soff[j] + (kk), dT + dbase + j * 512);                      \
  }

  STAGE(0, 0);
  { // load two q rows (pre-scaled fp16) into LDS
    const int li = tid >> 7;
    const int e  = (tid & 127) * 4;
    *(short4v*)(&qlds[li][e]) =
        *(const short4v*)(qh + (size_t)(b * 128 + l0 + li) * 512 + e);
  }
  __syncthreads();

  f32x4 acc[2][4][4] = {};
  int cur = 0;
  for (int t = 0; t < 8; ++t) {
    if (t < 7) STAGE(cur ^ 1, (t + 1) * 64);
    const _Float16* bufS = &buf[cur][0][0];
    const _Float16* bufT = &buf[cur][1][0];
    const int kk = t * 64;
#pragma unroll
    for (int s = 0; s < 2; ++s) {
      const int cg = s * 4 + (lane >> 4);
      half8 qv[2];
      qv[0] = *(const half8*)(&qlds[0][kk + cg * 8]);
      qv[1] = *(const half8*)(&qlds[1][kk + cg * 8]);
      half8 sfr[4], tfr[4];
#pragma unroll
      for (int mi = 0; mi < 4; ++mi) {
        const int row = wr * 64 + mi * 16 + (lane & 15);
        sfr[mi] = *(const half8*)(bufS + row * 64 + ((cg ^ (row & 7)) << 3));
      }
#pragma unroll
      for (int ni = 0; ni < 4; ++ni) {
        const int row = wc * 64 + ni * 16 + (lane & 15);
        tfr[ni] = *(const half8*)(bufT + row * 64 + ((cg ^ (row & 7)) << 3));
      }
#pragma unroll
      for (int li = 0; li < 2; ++li)
#pragma unroll
        for (int mi = 0; mi < 4; ++mi) {
          half8 a = sfr[mi] * qv[li];
#pragma unroll
          for (int ni = 0; ni < 4; ++ni)
            acc[li][mi][ni] =
                __builtin_amdgcn_mfma_f32_16x16x32_f16(a, tfr[ni], acc[li][mi][ni], 0, 0, 0);
        }
    }
    __syncthreads();
    cur ^= 1;
  }

  // ---- per-l global max ----
  float mx[2] = {-1e30f, -1e30f};
#pragma unroll
  for (int li = 0; li < 2; ++li)
#pragma unroll
    for (int mi = 0; mi < 4; ++mi)
#pragma unroll
      for (int ni = 0; ni < 4; ++ni)
#pragma unroll
        for (int r = 0; r < 4; ++r) mx[li] = fmaxf(mx[li], acc[li][mi][ni][r]);
#pragma unroll
  for (int li = 0; li < 2; ++li) {
#pragma unroll
    for (int off = 32; off >= 1; off >>= 1) mx[li] = fmaxf(mx[li], __shfl_xor(mx[li], off));
    if (lane == 0) red[li][wid] = mx[li];
  }
  __syncthreads();
  mx[0] = fmaxf(fmaxf(red[0][0], red[0][1]), fmaxf(red[0][2], red[0][3]));
  mx[1] = fmaxf(fmaxf(red[1][0], red[1][1]), fmaxf(red[1][2], red[1][3]));

  // ---- exp2 in place ----
#pragma unroll
  for (int li = 0; li < 2; ++li)
#pragma unroll
    for (int mi = 0; mi < 4; ++mi)
#pragma unroll
      for (int ni = 0; ni < 4; ++ni)
#pragma unroll
        for (int r = 0; r < 4; ++r)
          acc[li][mi][ni][r] = exp2f(acc[li][mi][ni][r] - mx[li]);

  // ---- row sums over t (C layout: col=lane&15, row=(lane>>4)*4+r) ----
#pragma unroll
  for (int li = 0; li < 2; ++li)
#pragma unroll
    for (int mi = 0; mi < 4; ++mi)
#pragma unroll
      for (int r = 0; r < 4; ++r) {
        float v = acc[li][mi][0][r] + acc[li][mi][1][r] + acc[li][mi][2][r] + acc[li][mi][3][r];
        v += __shfl_xor(v, 1, 16);
        v += __shfl_xor(v, 2, 16);
        v += __shfl_xor(v, 4, 16);
        v += __shfl_xor(v, 8, 16);
        if ((lane & 15) == 0)
          wsp[li][wc][wr * 64 + mi * 16 + ((lane >> 4) << 2) + r] = v;
      }
  // ---- col sums over s ----
#pragma unroll
  for (int li = 0; li < 2; ++li)
#pragma unroll
    for (int ni = 0; ni < 4; ++ni) {
      float v = 0.f;
#pragma unroll
      for (int mi = 0; mi < 4; ++mi)
#pragma unroll
        for (int r = 0; r < 4; ++r) v += acc[li][mi][ni][r];
      v += __shfl_xor(v, 16);
      v += __shfl_xor(v, 32);
      if (lane < 16) wtp[li][wr][wc * 64 + ni * 16 + lane] = v;
    }
  __syncthreads();
  if (tid < 128) {
    wfin[0][0][tid] = wsp[0][0][tid] + wsp[0][1][tid];
    wfin[1][0][tid] = wsp[1][0][tid] + wsp[1][1][tid];
  } else {
    const int u = tid - 128;
    wfin[0][1][u] = wtp[0][0][u] + wtp[0][1][u];
    wfin[1][1][u] = wtp[1][0][u] + wtp[1][1][u];
  }
  __syncthreads();
  if (wid < 2) {
    float v = wfin[wid][0][lane] + wfin[wid][0][lane + 64];
#pragma unroll
    for (int off = 32; off >= 1; off >>= 1) v += __shfl_xor(v, off);
    if (lane == 0) denom[wid] = v;
  }
  __syncthreads();
  const float invl[2] = {1.0f / denom[0], 1.0f / denom[1]};

  // ---- write normalized weights: wct[b][side][l][s] ----
  if (tid < 128) {
#pragma unroll
    for (int li = 0; li < 2; ++li)
      wct[((size_t)(b * 2 + 0) * 128 + l0 + li) * 128 + tid] =
          f2bfu(wfin[li][0][tid] * invl[li]);
  } else {
    const int u = tid - 128;
#pragma unroll
    for (int li = 0; li < 2; ++li)
      wct[((size_t)(b * 2 + 1) * 128 + l0 + li) * 128 + u] =
          f2bfu(wfin[li][1][u] * invl[li]);
  }
#undef STAGE
}

// ---------------------------------------------------------------------------
// K2b: contexts via MFMA: x[b,l, 512+side*512+f] = sum_s wct[b][side][l][s] * T[b][f][s]
// grid (side 2, fcol 4, b 16), block 256, tile 128l x 128f, K=128
// ---------------------------------------------------------------------------
__global__ __launch_bounds__(256) void k_ctx(const unsigned short* __restrict__ wct,
                                             const unsigned short* __restrict__ srcT,
                                             const unsigned short* __restrict__ trgT,
                                             unsigned short* __restrict__ x)
{
  __shared__ __align__(16) char stg[32768];
  const int side = blockIdx.x, fcol = blockIdx.y, b = blockIdx.z;
  const unsigned short* A  = wct + (size_t)(b * 2 + side) * 16384;
  const unsigned short* BT = (side ? trgT : srcT) + (size_t)b * 65536 + fcol * 16384;

  f32x4 acc[4][4] = {};
  gemm_tile<false>(A, BT, 128, 128, 128, stg, stg + 16384, acc);

  const int tid = threadIdx.x, lane = tid & 63;
  const int wr = (tid >> 7) & 1, wc = (tid >> 6) & 1;
  const int r0 = wr * 64 + ((lane >> 4) << 2);
  const int c0 = wc * 64 + (lane & 15);
  const int xoff = 512 + side * 512 + fcol * 128;
#pragma unroll
  for (int mi = 0; mi < 4; ++mi)
#pragma unroll
    for (int ni = 0; ni < 4; ++ni) {
      const int col = c0 + ni * 16;
#pragma unroll
      for (int r = 0; r < 4; ++r) {
        const int row = r0 + mi * 16 + r;
        x[(size_t)(b * 128 + row) * 1536 + xoff + col] = f2bfu(acc[mi][ni][r]);
      }
    }
}

// ---------------------------------------------------------------------------
// K3: out = x @ WoT^T + bo
// ---------------------------------------------------------------------------
__global__ __launch_bounds__(256) void k_out(const unsigned short* __restrict__ x,
                                             const unsigned short* __restrict__ WoT,
                                             const float* __restrict__ bo,
                                             float* __restrict__ out)
{
  __shared__ __align__(16) char stg[32768];
  const int brow = blockIdx.y * 128, bcol = blockIdx.x * 128;
  f32x4 acc[4][4] = {};
  gemm_tile<false>(x + (size_t)brow * 1536, WoT + (size_t)bcol * 1536,
                   1536, 1536, 1536, stg, stg + 16384, acc);
  const int tid = threadIdx.x, lane = tid & 63;
  const int wr = (tid >> 7) & 1, wc = (tid >> 6) & 1;
  const int r0 = wr * 64 + ((lane >> 4) << 2);
  const int c0 = wc * 64 + (lane & 15);
#pragma unroll
  for (int mi = 0; mi < 4; ++mi)
#pragma unroll
    for (int ni = 0; ni < 4; ++ni) {
      const int col = bcol + c0 + ni * 16;
      const float bv = bo[col];
#pragma unroll
      for (int r = 0; r < 4; ++r) {
        const int row = brow + r0 + mi * 16 + r;
        out[(size_t)row * 512 + col] = acc[mi][ni][r] + bv;
      }
    }
}

// ---------------------------------------------------------------------------
extern "C" void kernel_launch(void* const* d_in, const int* in_sizes, int n_in,
                              void* d_out, int out_size, void* d_ws, size_t ws_size,
                              hipStream_t stream)
{
  (void)in_sizes; (void)n_in; (void)out_size; (void)ws_size;
  const float* query = (const float*)d_in[0];
  const float* src   = (const float*)d_in[1];
  const float* trg   = (const float*)d_in[2];
  const float* Wq    = (const float*)d_in[3];
  const float* bq    = (const float*)d_in[4];
  const float* Ws    = (const float*)d_in[5];
  const float* bs    = (const float*)d_in[6];
  const float* Wo    = (const float*)d_in[7];
  const float* bo    = (const float*)d_in[8];
  float* out = (float*)d_out;

  char* w = (char*)d_ws;
  _Float16*       qh   = (_Float16*)(w);                            // 2 MiB
  _Float16*       skh  = (_Float16*)(w + (2u << 20));               // 2 MiB
  _Float16*       tkh  = (_Float16*)(w + (4u << 20));               // 2 MiB
  unsigned short* x    = (unsigned short*)(w + (6u << 20));         // 6 MiB bf16 [2048][1536]
  unsigned short* WqT  = (unsigned short*)(w + (12u << 20));        // 0.5 MiB
  unsigned short* WsT  = (unsigned short*)(w + (12u << 20) + 512 * 512 * 2);
  unsigned short* WoT  = (unsigned short*)(w + (13u << 20));        // 1.5 MiB
  unsigned short* srcT = (unsigned short*)(w + (15u << 20));        // 2 MiB bf16 [16][512][128]
  unsigned short* trgT = (unsigned short*)(w + (17u << 20));        // 2 MiB
  unsigned short* wct  = (unsigned short*)(w + (19u << 20));        // 1 MiB bf16 [16][2][128][128]

  k_transpose_cvt<<<dim3(16, 16, 1), 256, 0, stream>>>(Wq, WqT, 512, 512);
  k_transpose_cvt<<<dim3(16, 16, 1), 256, 0, stream>>>(Ws, WsT, 512, 512);
  k_transpose_cvt<<<dim3(16, 48, 1), 256, 0, stream>>>(Wo, WoT, 1536, 512);
  k_transpose_cvt<<<dim3(16, 4, 16), 256, 0, stream>>>(src, srcT, 128, 512);
  k_transpose_cvt<<<dim3(16, 4, 16), 256, 0, stream>>>(trg, trgT, 128, 512);
  k_cvt_query<<<512, 256, 0, stream>>>(query, x);
  k_proj<<<dim3(4, 16, 3), 256, 0, stream>>>(query, src, trg, WqT, WsT, bq, bs, qh, skh, tkh);
  k_score<<<1024, 256, 0, stream>>>(qh, skh, tkh, wct);
  k_ctx<<<dim3(2, 4, 16), 256, 0, stream>>>(wct, srcT, trgT, x);
  k_out<<<dim3(4, 16), 256, 0, stream>>>(x, WoT, bo, out);
}

// Round 4
// 109.234 us; speedup vs baseline: 1.6030x; 1.1367x over previous
//
#include <hip/hip_runtime.h>
#include <hip/hip_bf16.h>

typedef __attribute__((ext_vector_type(8))) short short8;
typedef __attribute__((ext_vector_type(4))) short short4v;
typedef __attribute__((ext_vector_type(4))) float f32x4;
typedef __attribute__((ext_vector_type(8))) _Float16 half8;

#define DEVINL static __device__ __forceinline__

constexpr float SCORE_SCALE = 0.063758977414048896f; // log2(e)/sqrt(512)

typedef const __attribute__((address_space(1))) void gv_t;
typedef __attribute__((address_space(3))) void lv_t;
DEVINL void gload16(const void* g, void* l) {
  __builtin_amdgcn_global_load_lds((gv_t*)g, (lv_t*)l, 16, 0, 0);
}

DEVINL float dswz_add(float v, const int pat_is_compiletime) { return v; } // unused

// butterfly add via ds_swizzle (xor within 32-lane groups)
#define SWZ_ADD(v, pat)                                                    \
  v += __int_as_float(__builtin_amdgcn_ds_swizzle(__float_as_int(v), pat))

// ---------------------------------------------------------------------------
// gemm16: C[128][128] = A[128xK] * B[128xK]^T, both fp16, 256 thr (2x2 waves).
// BK=64, double-buffered LDS via global_load_lds (linear dest, pre-swizzled
// global source, XOR-swizzled reads). __syncthreads per step (full drain).
// ---------------------------------------------------------------------------
DEVINL void gemm16(const _Float16* A, const _Float16* B, int K, int lda, int ldb,
                   _Float16* ldsA, _Float16* ldsB, f32x4 acc[4][4])
{
  const int tid = threadIdx.x, lane = tid & 63;
  const int wr = (tid >> 7) & 1, wc = (tid >> 6) & 1;
  int aoff[4], boff[4];
#pragma unroll
  for (int i = 0; i < 4; ++i) {
    const int ci = tid + i * 256, row = ci >> 3, c = ci & 7;
    const int sw = ((c ^ (row & 7)) << 3);
    aoff[i] = row * lda + sw;
    boff[i] = row * ldb + sw;
  }
#define G16STAGE(cur, kk)                                                     \
  {                                                                           \
    _Pragma("unroll")                                                         \
    for (int i = 0; i < 4; ++i) {                                             \
      gload16(A + aoff[i] + (kk), ldsA + (cur) * 8192 + (tid + i * 256) * 8); \
      gload16(B + boff[i] + (kk), ldsB + (cur) * 8192 + (tid + i * 256) * 8); \
    }                                                                         \
  }
  G16STAGE(0, 0);
  __syncthreads();
  for (int kk = 0; kk < K; kk += 64) {
    const int cur = (kk >> 6) & 1;
    if (kk + 64 < K) G16STAGE(cur ^ 1, kk + 64);
    const _Float16* bA = ldsA + cur * 8192;
    const _Float16* bB = ldsB + cur * 8192;
#pragma unroll
    for (int s = 0; s < 2; ++s) {
      const int cg = s * 4 + (lane >> 4);
      half8 afr[4], bfr[4];
#pragma unroll
      for (int mi = 0; mi < 4; ++mi) {
        const int r = wr * 64 + mi * 16 + (lane & 15);
        afr[mi] = *(const half8*)(bA + r * 64 + ((cg ^ (r & 7)) << 3));
      }
#pragma unroll
      for (int ni = 0; ni < 4; ++ni) {
        const int r = wc * 64 + ni * 16 + (lane & 15);
        bfr[ni] = *(const half8*)(bB + r * 64 + ((cg ^ (r & 7)) << 3));
      }
#pragma unroll
      for (int mi = 0; mi < 4; ++mi)
#pragma unroll
        for (int ni = 0; ni < 4; ++ni)
          acc[mi][ni] = __builtin_amdgcn_mfma_f32_16x16x32_f16(afr[mi], bfr[ni], acc[mi][ni], 0, 0, 0);
    }
    __syncthreads();
  }
#undef G16STAGE
}

// ---------------------------------------------------------------------------
// K0a: batched transpose + convert f32 -> fp16: out[z][n][k] = h(in[z][k][n])
// grid (NN/32, KK/32, batch), block 256
// ---------------------------------------------------------------------------
__global__ __launch_bounds__(256) void k_transpose_cvt(const float* __restrict__ in,
                                                       _Float16* __restrict__ out,
                                                       int KK, int NN)
{
  __shared__ float t[32][33];
  const size_t bo = (size_t)blockIdx.z * KK * NN;
  const int tx = threadIdx.x & 31, ty = threadIdx.x >> 5;
  const int k0 = blockIdx.y * 32, n0 = blockIdx.x * 32;
#pragma unroll
  for (int i = 0; i < 4; ++i)
    t[ty + i * 8][tx] = in[bo + (size_t)(k0 + ty + i * 8) * NN + n0 + tx];
  __syncthreads();
#pragma unroll
  for (int i = 0; i < 4; ++i)
    out[bo + (size_t)(n0 + ty + i * 8) * KK + k0 + tx] = (_Float16)t[tx][ty + i * 8];
}

// ---------------------------------------------------------------------------
// K0b: f32 -> fp16 converts. z=0: query -> x[:, 0:512] (stride 1536);
//      z=1: src -> srch; z=2: trg -> trgh
// grid (512, 3), block 256
// ---------------------------------------------------------------------------
__global__ __launch_bounds__(256) void k_cvt_in(const float* __restrict__ query,
                                                const float* __restrict__ src,
                                                const float* __restrict__ trg,
                                                _Float16* __restrict__ x,
                                                _Float16* __restrict__ srch,
                                                _Float16* __restrict__ trgh)
{
  const int z = blockIdx.y;
  const int idx8 = (blockIdx.x * 256 + threadIdx.x) * 8;
  const float* in = (z == 0) ? query : (z == 1) ? src : trg;
  float4 va = *(const float4*)(in + idx8);
  float4 vb = *(const float4*)(in + idx8 + 4);
  half8 h;
  h[0] = (_Float16)va.x; h[1] = (_Float16)va.y;
  h[2] = (_Float16)va.z; h[3] = (_Float16)va.w;
  h[4] = (_Float16)vb.x; h[5] = (_Float16)vb.y;
  h[6] = (_Float16)vb.z; h[7] = (_Float16)vb.w;
  if (z == 0) {
    const int row = idx8 >> 9, col = idx8 & 511;
    *(half8*)(x + (size_t)row * 1536 + col) = h;
  } else {
    _Float16* o = (z == 1) ? srch : trgh;
    *(half8*)(o + idx8) = h;
  }
}

// ---------------------------------------------------------------------------
// K1: projections (fp16 GEMM). z=0: qh=(x[:, :512]@WqT+bq)*SCALE;
//     z=1: skh=srch@WsT+bs; z=2: tkh=trgh@WsT+bs
// grid (4, 16, 3), block 256
// ---------------------------------------------------------------------------
__global__ __launch_bounds__(256) void k_proj(
    const _Float16* __restrict__ xq, const _Float16* __restrict__ srch,
    const _Float16* __restrict__ trgh,
    const _Float16* __restrict__ WqT, const _Float16* __restrict__ WsT,
    const float* __restrict__ bq, const float* __restrict__ bs,
    _Float16* __restrict__ qh, _Float16* __restrict__ skh,
    _Float16* __restrict__ tkh)
{
  __shared__ __align__(16) _Float16 lds[4][8192]; // [A0 A1 B0 B1]
  const int z = blockIdx.z;
  const _Float16* A = (z == 0) ? xq : (z == 1) ? srch : trgh;
  const int lda = (z == 0) ? 1536 : 512;
  const _Float16* BT = (z == 0) ? WqT : WsT;
  const float* bias = (z == 0) ? bq : bs;
  const int brow = blockIdx.y * 128, bcol = blockIdx.x * 128;

  f32x4 acc[4][4] = {};
  gemm16(A + (size_t)brow * lda, BT + (size_t)bcol * 512, 512, lda, 512,
         &lds[0][0], &lds[2][0], acc);

  const int tid = threadIdx.x, lane = tid & 63;
  const int wr = (tid >> 7) & 1, wc = (tid >> 6) & 1;
  const int r0 = wr * 64 + ((lane >> 4) << 2);
  const int c0 = wc * 64 + (lane & 15);
#pragma unroll
  for (int mi = 0; mi < 4; ++mi)
#pragma unroll
    for (int ni = 0; ni < 4; ++ni) {
      const int col = bcol + c0 + ni * 16;
      const float bv = bias[col];
#pragma unroll
      for (int r = 0; r < 4; ++r) {
        const int row = brow + r0 + mi * 16 + r;
        const float v = acc[mi][ni][r] + bv;
        if (z == 0)      qh[(size_t)row * 512 + col] = (_Float16)(v * SCORE_SCALE);
        else if (z == 1) skh[(size_t)row * 512 + col] = (_Float16)v;
        else             tkh[(size_t)row * 512 + col] = (_Float16)v;
      }
    }
}

// ---------------------------------------------------------------------------
// K2: per-(b, l-pair) trilinear scores + softmax -> normalized ws/wt (fp16)
// Triple-buffered BK=32, counted vmcnt (T3+T4), raw s_barrier. grid 1024.
// ---------------------------------------------------------------------------
__global__ __launch_bounds__(256, 2) void k_score(
    const _Float16* __restrict__ qh, const _Float16* __restrict__ skh,
    const _Float16* __restrict__ tkh,
    _Float16* __restrict__ wct)
{
  // pool: buf0 @0, buf1 @16384, buf2 @32768 (each: S 8192B + T 8192B), q @49152
  // softmax scratch aliases buf0 (used only after the K-loop).
  __shared__ __align__(16) char pool[51200];
  _Float16* qlds = (_Float16*)(pool + 49152);
  float* wsp   = (float*)(pool);           // [2][2][128]
  float* wtp   = (float*)(pool + 2048);    // [2][2][128]
  float* wfin  = (float*)(pool + 4096);    // [2][2][128]
  float* red   = (float*)(pool + 6144);    // [2][4]
  float* denom = (float*)(pool + 6176);    // [2]

  // bijective XCD swizzle: same-b blocks share an XCD L2
  const int raw = blockIdx.x;
  const int swz = (raw & 7) * 128 + (raw >> 3);
  const int b = swz >> 6, l0 = (swz & 63) * 2;

  const int tid = threadIdx.x, lane = tid & 63, wid = tid >> 6;
  const int wr = wid >> 1, wc = wid & 1;
  const _Float16* skb = skh + (size_t)b * 65536;
  const _Float16* tkb = tkh + (size_t)b * 65536;

  // q rows -> LDS (issued before stages; prologue drains vmcnt anyway)
  {
    const int li = tid >> 7, e = (tid & 127) * 4;
    *(short4v*)(qlds + li * 512 + e) =
        *(const short4v*)(qh + (size_t)(b * 128 + l0 + li) * 512 + e);
  }

  // stage source offsets: chunk ci = j*256+tid; row=ci>>2, c=ci&3 (32-half rows)
  int soff[2];
#pragma unroll
  for (int j = 0; j < 2; ++j) {
    const int ci = j * 256 + tid;
    const int row = ci >> 2, c = ci & 3;
    soff[j] = row * 512 + ((c ^ (row & 3)) << 3);
  }

  // fragment read byte-offsets (t-invariant; buffer base rotates)
  const int cg = lane >> 4;
  int sfrOff[4], tfrOff[4];
#pragma unroll
  for (int mi = 0; mi < 4; ++mi) {
    const int r = wr * 64 + mi * 16 + (lane & 15);
    sfrOff[mi] = r * 64 + ((cg ^ (r & 3)) << 4);
  }
#pragma unroll
  for (int ni = 0; ni < 4; ++ni) {
    const int r = wc * 64 + ni * 16 + (lane & 15);
    tfrOff[ni] = r * 64 + ((cg ^ (r & 3)) << 4);
  }

#define KSTAGE(dst, kt)                                                    \
  {                                                                        \
    _Float16* dS = (_Float16*)(dst);                                       \
    _Float16* dT = (_Float16*)((dst) + 8192);                              \
    _Pragma("unroll")                                                      \
    for (int j = 0; j < 2; ++j) {                                          \
      gload16(skb + soff[j] + (kt) * 32, dS + (j * 256 + tid) * 8);        \
      gload16(tkb + soff[j] + (kt) * 32, dT + (j * 256 + tid) * 8);        \
    }                                                                      \
  }

  char* bA = pool;
  char* bB = pool + 16384;
  char* bC = pool + 32768;

  KSTAGE(bA, 0);
  KSTAGE(bB, 1);
  asm volatile("s_waitcnt vmcnt(0) lgkmcnt(0)" ::: "memory");
  __builtin_amdgcn_sched_barrier(0);
  __builtin_amdgcn_s_barrier();
  __builtin_amdgcn_sched_barrier(0);

  f32x4 acc[2][4][4] = {};
  for (int t = 0; t < 16; ++t) {
    if (t < 14) KSTAGE(bC, t + 2);
    half8 qv0 = *(const half8*)(qlds + t * 32 + cg * 8);
    half8 qv1 = *(const half8*)(qlds + 512 + t * 32 + cg * 8);
    half8 sfr[4], tfr[4];
#pragma unroll
    for (int mi = 0; mi < 4; ++mi) sfr[mi] = *(const half8*)(bA + sfrOff[mi]);
#pragma unroll
    for (int ni = 0; ni < 4; ++ni) tfr[ni] = *(const half8*)(bA + 8192 + tfrOff[ni]);
#pragma unroll
    for (int mi = 0; mi < 4; ++mi) {
      half8 a0 = sfr[mi] * qv0;
      half8 a1 = sfr[mi] * qv1;
#pragma unroll
      for (int ni = 0; ni < 4; ++ni) {
        acc[0][mi][ni] = __builtin_amdgcn_mfma_f32_16x16x32_f16(a0, tfr[ni], acc[0][mi][ni], 0, 0, 0);
        acc[1][mi][ni] = __builtin_amdgcn_mfma_f32_16x16x32_f16(a1, tfr[ni], acc[1][mi][ni], 0, 0, 0);
      }
    }
    if (t < 14) { asm volatile("s_waitcnt vmcnt(4)" ::: "memory"); }
    else        { asm volatile("s_waitcnt vmcnt(0)" ::: "memory"); }
    __builtin_amdgcn_sched_barrier(0);
    __builtin_amdgcn_s_barrier();
    __builtin_amdgcn_sched_barrier(0);
    char* tmp = bA; bA = bB; bB = bC; bC = tmp;
  }
#undef KSTAGE

  // ---- per-l global max ----
  float mx[2] = {-1e30f, -1e30f};
#pragma unroll
  for (int li = 0; li < 2; ++li)
#pragma unroll
    for (int mi = 0; mi < 4; ++mi)
#pragma unroll
      for (int ni = 0; ni < 4; ++ni)
#pragma unroll
        for (int r = 0; r < 4; ++r) mx[li] = fmaxf(mx[li], acc[li][mi][ni][r]);
#pragma unroll
  for (int li = 0; li < 2; ++li) {
#pragma unroll
    for (int off = 32; off >= 1; off >>= 1) mx[li] = fmaxf(mx[li], __shfl_xor(mx[li], off));
    if (lane == 0) red[li * 4 + wid] = mx[li];
  }
  __syncthreads();
  mx[0] = fmaxf(fmaxf(red[0], red[1]), fmaxf(red[2], red[3]));
  mx[1] = fmaxf(fmaxf(red[4], red[5]), fmaxf(red[6], red[7]));

  // ---- exp2 in place ----
#pragma unroll
  for (int li = 0; li < 2; ++li)
#pragma unroll
    for (int mi = 0; mi < 4; ++mi)
#pragma unroll
      for (int ni = 0; ni < 4; ++ni)
#pragma unroll
        for (int r = 0; r < 4; ++r)
          acc[li][mi][ni][r] = exp2f(acc[li][mi][ni][r] - mx[li]);

  // ---- row sums over t (C layout: col=lane&15, row=(lane>>4)*4+r) ----
#pragma unroll
  for (int li = 0; li < 2; ++li)
#pragma unroll
    for (int mi = 0; mi < 4; ++mi)
#pragma unroll
      for (int r = 0; r < 4; ++r) {
        float v = acc[li][mi][0][r] + acc[li][mi][1][r] + acc[li][mi][2][r] + acc[li][mi][3][r];
        SWZ_ADD(v, 0x041F);
        SWZ_ADD(v, 0x081F);
        SWZ_ADD(v, 0x101F);
        SWZ_ADD(v, 0x201F);
        if ((lane & 15) == 0)
          wsp[(li * 2 + wc) * 128 + wr * 64 + mi * 16 + ((lane >> 4) << 2) + r] = v;
      }
  // ---- col sums over s ----
#pragma unroll
  for (int li = 0; li < 2; ++li)
#pragma unroll
    for (int ni = 0; ni < 4; ++ni) {
      float v = 0.f;
#pragma unroll
      for (int mi = 0; mi < 4; ++mi)
#pragma unroll
        for (int r = 0; r < 4; ++r) v += acc[li][mi][ni][r];
      SWZ_ADD(v, 0x401F);
      v += __shfl_xor(v, 32);
      if (lane < 16) wtp[(li * 2 + wr) * 128 + wc * 64 + ni * 16 + lane] = v;
    }
  __syncthreads();
  if (tid < 128) {
    wfin[0 * 128 + tid] = wsp[0 * 128 + tid] + wsp[1 * 128 + tid];
    wfin[2 * 128 + tid] = wsp[2 * 128 + tid] + wsp[3 * 128 + tid];
  } else {
    const int u = tid - 128;
    wfin[1 * 128 + u] = wtp[0 * 128 + u] + wtp[1 * 128 + u];
    wfin[3 * 128 + u] = wtp[2 * 128 + u] + wtp[3 * 128 + u];
  }
  __syncthreads();
  if (wid < 2) {
    float v = wfin[wid * 256 + lane] + wfin[wid * 256 + lane + 64];
#pragma unroll
    for (int off = 32; off >= 1; off >>= 1) v += __shfl_xor(v, off);
    if (lane == 0) denom[wid] = v;
  }
  __syncthreads();
  const float inv0 = 1.0f / denom[0], inv1 = 1.0f / denom[1];

  // ---- write normalized weights: wct[b][side][l][s] ----
  if (tid < 128) {
    wct[((size_t)(b * 2 + 0) * 128 + l0 + 0) * 128 + tid] = (_Float16)(wfin[0 * 128 + tid] * inv0);
    wct[((size_t)(b * 2 + 0) * 128 + l0 + 1) * 128 + tid] = (_Float16)(wfin[2 * 128 + tid] * inv1);
  } else {
    const int u = tid - 128;
    wct[((size_t)(b * 2 + 1) * 128 + l0 + 0) * 128 + u] = (_Float16)(wfin[1 * 128 + u] * inv0);
    wct[((size_t)(b * 2 + 1) * 128 + l0 + 1) * 128 + u] = (_Float16)(wfin[3 * 128 + u] * inv1);
  }
}

// ---------------------------------------------------------------------------
// K2b: contexts: x[b,l, 512+side*512+fcol*128+f] = sum_s wct[b][side][l][s]*T[b][f][s]
// grid (side 2, fcol 4, b 16), block 256
// ---------------------------------------------------------------------------
__global__ __launch_bounds__(256) void k_ctx(const _Float16* __restrict__ wct,
                                             const _Float16* __restrict__ srcT,
                                             const _Float16* __restrict__ trgT,
                                             _Float16* __restrict__ x)
{
  __shared__ __align__(16) _Float16 lds[4][8192];
  const int side = blockIdx.x, fcol = blockIdx.y, b = blockIdx.z;
  const _Float16* A  = wct + (size_t)(b * 2 + side) * 16384;
  const _Float16* BT = (side ? trgT : srcT) + (size_t)b * 65536 + fcol * 16384;

  f32x4 acc[4][4] = {};
  gemm16(A, BT, 128, 128, 128, &lds[0][0], &lds[2][0], acc);

  const int tid = threadIdx.x, lane = tid & 63;
  const int wr = (tid >> 7) & 1, wc = (tid >> 6) & 1;
  const int r0 = wr * 64 + ((lane >> 4) << 2);
  const int c0 = wc * 64 + (lane & 15);
  const int xoff = 512 + side * 512 + fcol * 128;
#pragma unroll
  for (int mi = 0; mi < 4; ++mi)
#pragma unroll
    for (int ni = 0; ni < 4; ++ni) {
      const int col = c0 + ni * 16;
#pragma unroll
      for (int r = 0; r < 4; ++r) {
        const int row = r0 + mi * 16 + r;
        x[(size_t)(b * 128 + row) * 1536 + xoff + col] = (_Float16)acc[mi][ni][r];
      }
    }
}

// ---------------------------------------------------------------------------
// K3: out = x @ WoT^T + bo   (fp16 x [2048][1536], fp16 WoT [512][1536])
// grid (4, 16), block 256
// ---------------------------------------------------------------------------
__global__ __launch_bounds__(256) void k_out(const _Float16* __restrict__ x,
                                             const _Float16* __restrict__ WoT,
                                             const float* __restrict__ bo,
                                             float* __restrict__ out)
{
  __shared__ __align__(16) _Float16 lds[4][8192];
  const int brow = blockIdx.y * 128, bcol = blockIdx.x * 128;
  f32x4 acc[4][4] = {};
  gemm16(x + (size_t)brow * 1536, WoT + (size_t)bcol * 1536, 1536, 1536, 1536,
         &lds[0][0], &lds[2][0], acc);
  const int tid = threadIdx.x, lane = tid & 63;
  const int wr = (tid >> 7) & 1, wc = (tid >> 6) & 1;
  const int r0 = wr * 64 + ((lane >> 4) << 2);
  const int c0 = wc * 64 + (lane & 15);
#pragma unroll
  for (int mi = 0; mi < 4; ++mi)
#pragma unroll
    for (int ni = 0; ni < 4; ++ni) {
      const int col = bcol + c0 + ni * 16;
      const float bv = bo[col];
#pragma unroll
      for (int r = 0; r < 4; ++r) {
        const int row = brow + r0 + mi * 16 + r;
        out[(size_t)row * 512 + col] = acc[mi][ni][r] + bv;
      }
    }
}

// ---------------------------------------------------------------------------
extern "C" void kernel_launch(void* const* d_in, const int* in_sizes, int n_in,
                              void* d_out, int out_size, void* d_ws, size_t ws_size,
                              hipStream_t stream)
{
  (void)in_sizes; (void)n_in; (void)out_size; (void)ws_size;
  const float* query = (const float*)d_in[0];
  const float* src   = (const float*)d_in[1];
  const float* trg   = (const float*)d_in[2];
  const float* Wq    = (const float*)d_in[3];
  const float* bq    = (const float*)d_in[4];
  const float* Ws    = (const float*)d_in[5];
  const float* bs    = (const float*)d_in[6];
  const float* Wo    = (const float*)d_in[7];
  const float* bo    = (const float*)d_in[8];
  float* out = (float*)d_out;

  char* w = (char*)d_ws;
  _Float16* x    = (_Float16*)(w);                    // 6 MiB [2048][1536]
  _Float16* qh   = (_Float16*)(w + (6u  << 20));      // 2 MiB [2048][512]
  _Float16* skh  = (_Float16*)(w + (8u  << 20));      // 2 MiB
  _Float16* tkh  = (_Float16*)(w + (10u << 20));      // 2 MiB
  _Float16* srch = (_Float16*)(w + (12u << 20));      // 2 MiB
  _Float16* trgh = (_Float16*)(w + (14u << 20));      // 2 MiB
  _Float16* WqT  = (_Float16*)(w + (16u << 20));      // 0.5 MiB [512][512]
  _Float16* WsT  = (_Float16*)(w + (16u << 20) + 512 * 512 * 2);
  _Float16* WoT  = (_Float16*)(w + (17u << 20));      // 1.5 MiB [512][1536]
  _Float16* srcT = (_Float16*)(w + (19u << 20));      // 2 MiB [16][512][128]
  _Float16* trgT = (_Float16*)(w + (21u << 20));      // 2 MiB
  _Float16* wct  = (_Float16*)(w + (23u << 20));      // 1 MiB [16][2][128][128]

  k_cvt_in<<<dim3(512, 3), 256, 0, stream>>>(query, src, trg, x, srch, trgh);
  k_transpose_cvt<<<dim3(16, 16, 1), 256, 0, stream>>>(Wq, WqT, 512, 512);
  k_transpose_cvt<<<dim3(16, 16, 1), 256, 0, stream>>>(Ws, WsT, 512, 512);
  k_transpose_cvt<<<dim3(16, 48, 1), 256, 0, stream>>>(Wo, WoT, 1536, 512);
  k_transpose_cvt<<<dim3(16, 4, 16), 256, 0, stream>>>(src, srcT, 128, 512);
  k_transpose_cvt<<<dim3(16, 4, 16), 256, 0, stream>>>(trg, trgT, 128, 512);
  k_proj<<<dim3(4, 16, 3), 256, 0, stream>>>(x, srch, trgh, WqT, WsT, bq, bs, qh, skh, tkh);
  k_score<<<1024, 256, 0, stream>>>(qh, skh, tkh, wct);
  k_ctx<<<dim3(2, 4, 16), 256, 0, stream>>>(wct, srcT, trgT, x);
  k_out<<<dim3(4, 16), 256, 0, stream>>>(x, WoT, bo, out);
}